// Round 13
// baseline (707.658 us; speedup 1.0000x reference)
//
#include <hip/hip_runtime.h>
#include <math.h>

// ---------------------------------------------------------------------------
// GNN: 3x GCNConv(edge-weighted, self-loops) + SiLU, mean-pool, MLP.
// R1: CSR-by-dst + gather.  R2: two-stage pool.  R3: scaled features h'=h*dinv.
// R5: register-disciplined layer-3 GEMM.  R6: counting-sort CSR build.
// R7: fused layer3 GEMM+pool; gather+xform1/2 fused.  R8: POOL_C=8.
// R9: dl packed in ebuf.x[31:24].  R10: gx contiguous quarters ILP8; 8n/wave GEMM.
// R11: fixed-capacity padded buckets; offs packed pos|(len<<24).
// R12: non-temporal hints on all single-use streams (csr reads, src/ew reads,
//      ebuf/csr/h2s/y64 writes) to stop them evicting the reused feature
//      tables from L2 — targets gather64's stuck FETCH=382MB (table is 25.6MB).
// ---------------------------------------------------------------------------

#define NBH 256       // scatter blocks
#define POOL_C 8      // chunks per graph for fused GEMM+pool (512 blocks = 2/CU)
#define X3T 32        // nodes per tile in xform3pool (8 per wave)
#define CAP 10240     // padded bucket capacity (mean 8184, sigma~90)

__device__ __forceinline__ float silu_f(float v) { return v / (1.0f + expf(-v)); }
__device__ __forceinline__ void fma4(float4& a, float s, const float4& w) {
    a.x += s * w.x; a.y += s * w.y; a.z += s * w.z; a.w += s * w.w;
}
// non-temporal 8B load/store of an int2 (single-use streams)
__device__ __forceinline__ int2 ldnt_i2(const int2* p) {
    unsigned long long v = __builtin_nontemporal_load((const unsigned long long*)p);
    int2 r; r.x = (int)(unsigned)(v & 0xFFFFFFFFull); r.y = (int)(unsigned)(v >> 32);
    return r;
}
__device__ __forceinline__ void stnt_i2(int2* p, int2 val) {
    unsigned long long v = ((unsigned long long)(unsigned)val.y << 32) | (unsigned)val.x;
    __builtin_nontemporal_store(v, (unsigned long long*)p);
}

// ---- init: zero bucket cursors + graph boundaries (one tiny block) ----
__global__ void k_init(const int* __restrict__ batch, int* __restrict__ bounds,
                       int* __restrict__ btotal, int N, int G) {
    int t = threadIdx.x;
    btotal[t] = 0;                     // 512 threads, 512 ints
    if (t > G) return;
    if (t == G) { bounds[G] = N; return; }
    int lo = 0, hi = N;
    while (lo < hi) { int m = (lo + hi) >> 1; if (batch[m] < t) lo = m + 1; else hi = m; }
    bounds[t] = lo;
}

// ---- count + reserve + scatter into statically-based padded buckets ----
__global__ __launch_bounds__(256) void k_bscatter(const int* __restrict__ src,
                                                  const int* __restrict__ dst,
                                                  const float* __restrict__ ew,
                                                  int* __restrict__ btotal,
                                                  int2* __restrict__ ebuf,
                                                  int E, int B, int ept) {
    __shared__ int hist[512];
    __shared__ int cur[512];
    int blk = blockIdx.x, t = threadIdx.x;
    for (int i = t; i < B; i += 256) hist[i] = 0;
    __syncthreads();
    int start = blk * 256 * ept;
    for (int j = 0; j < ept; j++) {
        int e = start + j * 256 + t;
        if (e < E) atomicAdd(&hist[dst[e] >> 8], 1);   // dst cached (re-read below)
    }
    __syncthreads();
    for (int b = t; b < B; b += 256)
        cur[b] = b * CAP + atomicAdd(&btotal[b], hist[b]);
    __syncthreads();
    for (int j = 0; j < ept; j++) {
        int e = start + j * 256 + t;
        if (e < E) {
            int d = dst[e];                            // L2-warm from pass 1
            int s = __builtin_nontemporal_load(&src[e]);   // single-use stream
            float w = __builtin_nontemporal_load(&ew[e]);  // single-use stream
            int b = d >> 8;
            int pos = atomicAdd(&cur[b], 1);
            if (pos < (b + 1) * CAP)   // 23-sigma margin; clamp for safety
                stnt_i2(&ebuf[pos], make_int2(s | ((d & 255) << 24), __float_as_int(w)));
        }
    }
}

// ---- per-bucket node grouping -> padded CSR + packed offs + dinv + xp ----
__global__ __launch_bounds__(256) void k_bucket_csr(const int2* __restrict__ ebuf,
                                                    const int* __restrict__ btotal,
                                                    int2* __restrict__ csr,
                                                    unsigned int* __restrict__ offs,
                                                    float* __restrict__ dinv,
                                                    const float* __restrict__ x,
                                                    float* __restrict__ xp,
                                                    int N) {
    __shared__ int ncnt[256];
    __shared__ int excl[256];
    __shared__ float wsum[256];
    int b = blockIdx.x, t = threadIdx.x;
    int base = b * CAP;
    int end = base + min(btotal[b], CAP);
    ncnt[t] = 0;
    wsum[t] = 0.0f;
    __syncthreads();
    for (int i = base + t; i < end; i += 256)
        atomicAdd(&ncnt[(unsigned)ebuf[i].x >> 24], 1);   // ebuf cached: re-read below
    __syncthreads();
    int v = ncnt[t];
    excl[t] = v;
    __syncthreads();
#pragma unroll
    for (int o = 1; o < 256; o <<= 1) {
        int x2 = (t >= o) ? excl[t - o] : 0;
        __syncthreads();
        excl[t] += x2;
        __syncthreads();
    }
    int ex = excl[t] - v;                 // exclusive prefix within bucket
    int n = (b << 8) + t;
    if (n < N) offs[n] = (unsigned)(base + ex) | ((unsigned)v << 24);
    __syncthreads();
    ncnt[t] = base + ex;                  // reuse as per-node cursor
    __syncthreads();
    for (int i = base + t; i < end; i += 256) {
        int2 ent = ebuf[i];
        int node = (unsigned)ent.x >> 24;
        int pos = atomicAdd(&ncnt[node], 1);
        stnt_i2(&csr[pos], make_int2(ent.x & 0x00FFFFFF, ent.y));  // single-use-per-kernel stream
        atomicAdd(&wsum[node], __int_as_float(ent.y));
    }
    __syncthreads();
    if (n < N) {
        float dv = 1.0f / sqrtf(1.0f + wsum[t]);
        dinv[n] = dv;
        const float4* xr = (const float4*)(x + (long long)n * 16);
        float4* xw = (float4*)(xp + (long long)n * 16);
#pragma unroll
        for (int j = 0; j < 4; j++) {
            float4 vv = xr[j];
            vv.x *= dv; vv.y *= dv; vv.z *= dv; vv.w *= dv;
            xw[j] = vv;
        }
    }
}

// ---- fused gather16 + 16->16 GEMM + silu: h1 = silu(y@W1+b1)*dinv ----
// Edge-group eg owns a CONTIGUOUS quarter of the row, ILP8; csr loads nt.
__global__ __launch_bounds__(256) void k_gx1(const float* __restrict__ h,
                                             const int2* __restrict__ csr,
                                             const unsigned int* __restrict__ offs,
                                             const float* __restrict__ dinv,
                                             const float* __restrict__ W,
                                             const float* __restrict__ b,
                                             float* __restrict__ out, int N) {
    __shared__ float Ws[16 * 16];
    __shared__ float bs[16];
    if (threadIdx.x < 256) Ws[threadIdx.x] = W[threadIdx.x];
    if (threadIdx.x < 16) bs[threadIdx.x] = b[threadIdx.x];
    __syncthreads();
    int n = blockIdx.x * 4 + (threadIdx.x >> 6);
    n = __builtin_amdgcn_readfirstlane(n);
    if (n >= N) return;
    int lane = threadIdx.x & 63;
    int d = lane & 15, eg = lane >> 4;
    unsigned op = offs[n];
    int p0 = op & 0x00FFFFFF;
    int len = op >> 24;
    int qs = p0 + ((len * eg) >> 2);
    int qe = p0 + ((len * (eg + 1)) >> 2);
    float acc = 0.0f;
    int p = qs;
    for (; p + 7 < qe; p += 8) {
        int2 e0 = ldnt_i2(&csr[p]),     e1 = ldnt_i2(&csr[p + 1]);
        int2 e2 = ldnt_i2(&csr[p + 2]), e3 = ldnt_i2(&csr[p + 3]);
        int2 e4 = ldnt_i2(&csr[p + 4]), e5 = ldnt_i2(&csr[p + 5]);
        int2 e6 = ldnt_i2(&csr[p + 6]), e7 = ldnt_i2(&csr[p + 7]);
        float v0 = h[e0.x * 16 + d], v1 = h[e1.x * 16 + d];
        float v2 = h[e2.x * 16 + d], v3 = h[e3.x * 16 + d];
        float v4 = h[e4.x * 16 + d], v5 = h[e5.x * 16 + d];
        float v6 = h[e6.x * 16 + d], v7 = h[e7.x * 16 + d];
        acc += __int_as_float(e0.y) * v0; acc += __int_as_float(e1.y) * v1;
        acc += __int_as_float(e2.y) * v2; acc += __int_as_float(e3.y) * v3;
        acc += __int_as_float(e4.y) * v4; acc += __int_as_float(e5.y) * v5;
        acc += __int_as_float(e6.y) * v6; acc += __int_as_float(e7.y) * v7;
    }
    if (p + 3 < qe) {
        int2 e0 = ldnt_i2(&csr[p]),     e1 = ldnt_i2(&csr[p + 1]);
        int2 e2 = ldnt_i2(&csr[p + 2]), e3 = ldnt_i2(&csr[p + 3]);
        float v0 = h[e0.x * 16 + d], v1 = h[e1.x * 16 + d];
        float v2 = h[e2.x * 16 + d], v3 = h[e3.x * 16 + d];
        acc += __int_as_float(e0.y) * v0; acc += __int_as_float(e1.y) * v1;
        acc += __int_as_float(e2.y) * v2; acc += __int_as_float(e3.y) * v3;
        p += 4;
    }
    if (p + 1 < qe) {
        int2 e0 = ldnt_i2(&csr[p]), e1 = ldnt_i2(&csr[p + 1]);
        acc += __int_as_float(e0.y) * h[e0.x * 16 + d];
        acc += __int_as_float(e1.y) * h[e1.x * 16 + d];
        p += 2;
    }
    if (p < qe) {
        int2 e0 = ldnt_i2(&csr[p]);
        acc += __int_as_float(e0.y) * h[e0.x * 16 + d];
    }
    acc += __shfl_down(acc, 32, 64);
    acc += __shfl_down(acc, 16, 64);
    float dv = dinv[n];
    float yv = (acc + ((lane < 16) ? h[n * 16 + lane] : 0.0f)) * dv;
    float o = bs[d];
#pragma unroll
    for (int k = 0; k < 16; k++) o += __shfl(yv, k, 64) * Ws[k * 16 + d];
    if (lane < 16) out[n * 16 + lane] = silu_f(o) * dv;
}

// ---- fused gather16 + 16->64 GEMM + silu: h2 = silu(y@W2+b2)*dinv ----
// csr loads nt; h2s output store nt (protects h1s table in L2).
__global__ __launch_bounds__(256) void k_gx2(const float* __restrict__ h,
                                             const int2* __restrict__ csr,
                                             const unsigned int* __restrict__ offs,
                                             const float* __restrict__ dinv,
                                             const float* __restrict__ W,
                                             const float* __restrict__ b,
                                             float* __restrict__ out, int N) {
    __shared__ float Ws[16 * 64];
    __shared__ float bs[64];
    for (int i = threadIdx.x; i < 16 * 64; i += 256) Ws[i] = W[i];
    if (threadIdx.x < 64) bs[threadIdx.x] = b[threadIdx.x];
    __syncthreads();
    int n = blockIdx.x * 4 + (threadIdx.x >> 6);
    n = __builtin_amdgcn_readfirstlane(n);
    if (n >= N) return;
    int lane = threadIdx.x & 63;
    int d = lane & 15, eg = lane >> 4;
    unsigned op = offs[n];
    int p0 = op & 0x00FFFFFF;
    int len = op >> 24;
    int qs = p0 + ((len * eg) >> 2);
    int qe = p0 + ((len * (eg + 1)) >> 2);
    float acc = 0.0f;
    int p = qs;
    for (; p + 7 < qe; p += 8) {
        int2 e0 = ldnt_i2(&csr[p]),     e1 = ldnt_i2(&csr[p + 1]);
        int2 e2 = ldnt_i2(&csr[p + 2]), e3 = ldnt_i2(&csr[p + 3]);
        int2 e4 = ldnt_i2(&csr[p + 4]), e5 = ldnt_i2(&csr[p + 5]);
        int2 e6 = ldnt_i2(&csr[p + 6]), e7 = ldnt_i2(&csr[p + 7]);
        float v0 = h[e0.x * 16 + d], v1 = h[e1.x * 16 + d];
        float v2 = h[e2.x * 16 + d], v3 = h[e3.x * 16 + d];
        float v4 = h[e4.x * 16 + d], v5 = h[e5.x * 16 + d];
        float v6 = h[e6.x * 16 + d], v7 = h[e7.x * 16 + d];
        acc += __int_as_float(e0.y) * v0; acc += __int_as_float(e1.y) * v1;
        acc += __int_as_float(e2.y) * v2; acc += __int_as_float(e3.y) * v3;
        acc += __int_as_float(e4.y) * v4; acc += __int_as_float(e5.y) * v5;
        acc += __int_as_float(e6.y) * v6; acc += __int_as_float(e7.y) * v7;
    }
    if (p + 3 < qe) {
        int2 e0 = ldnt_i2(&csr[p]),     e1 = ldnt_i2(&csr[p + 1]);
        int2 e2 = ldnt_i2(&csr[p + 2]), e3 = ldnt_i2(&csr[p + 3]);
        float v0 = h[e0.x * 16 + d], v1 = h[e1.x * 16 + d];
        float v2 = h[e2.x * 16 + d], v3 = h[e3.x * 16 + d];
        acc += __int_as_float(e0.y) * v0; acc += __int_as_float(e1.y) * v1;
        acc += __int_as_float(e2.y) * v2; acc += __int_as_float(e3.y) * v3;
        p += 4;
    }
    if (p + 1 < qe) {
        int2 e0 = ldnt_i2(&csr[p]), e1 = ldnt_i2(&csr[p + 1]);
        acc += __int_as_float(e0.y) * h[e0.x * 16 + d];
        acc += __int_as_float(e1.y) * h[e1.x * 16 + d];
        p += 2;
    }
    if (p < qe) {
        int2 e0 = ldnt_i2(&csr[p]);
        acc += __int_as_float(e0.y) * h[e0.x * 16 + d];
    }
    acc += __shfl_down(acc, 32, 64);
    acc += __shfl_down(acc, 16, 64);
    float dv = dinv[n];
    float yv = (acc + ((lane < 16) ? h[n * 16 + lane] : 0.0f)) * dv;
    float o = bs[lane];
#pragma unroll
    for (int k = 0; k < 16; k++) o += __shfl(yv, k, 64) * Ws[k * 64 + lane];
    __builtin_nontemporal_store(silu_f(o) * dv, &out[(long long)n * 64 + lane]);
}

// ---- gather D=64 + self term, ILP 8 main + ILP 4 tail; csr nt, y store nt ----
__global__ __launch_bounds__(256) void k_gather64(const float* __restrict__ h,
                                                  const int2* __restrict__ csr,
                                                  const unsigned int* __restrict__ offs,
                                                  const float* __restrict__ dinv,
                                                  float* __restrict__ y, int N) {
    int n = blockIdx.x * 4 + (threadIdx.x >> 6);
    n = __builtin_amdgcn_readfirstlane(n);
    if (n >= N) return;
    int lane = threadIdx.x & 63;
    unsigned op = offs[n];
    const int2* row = csr + (op & 0x00FFFFFF);
    int len = op >> 24;
    float acc = 0.0f;
    int j = 0;
    for (; j + 7 < len; j += 8) {
        int2 ee[8];
        float vv[8];
#pragma unroll
        for (int i = 0; i < 8; i++) ee[i] = ldnt_i2(&row[j + i]);
#pragma unroll
        for (int i = 0; i < 8; i++) vv[i] = h[ee[i].x * 64 + lane];
#pragma unroll
        for (int i = 0; i < 8; i++) acc += __int_as_float(ee[i].y) * vv[i];
    }
    if (j + 3 < len) {                     // ILP 4 tail
        int2 e0 = ldnt_i2(&row[j]),     e1 = ldnt_i2(&row[j + 1]);
        int2 e2 = ldnt_i2(&row[j + 2]), e3 = ldnt_i2(&row[j + 3]);
        float v0 = h[e0.x * 64 + lane];
        float v1 = h[e1.x * 64 + lane];
        float v2 = h[e2.x * 64 + lane];
        float v3 = h[e3.x * 64 + lane];
        acc += __int_as_float(e0.y) * v0;
        acc += __int_as_float(e1.y) * v1;
        acc += __int_as_float(e2.y) * v2;
        acc += __int_as_float(e3.y) * v3;
        j += 4;
    }
    for (; j < len; j++) {
        int2 e0 = ldnt_i2(&row[j]);
        acc += __int_as_float(e0.y) * h[e0.x * 64 + lane];
    }
    __builtin_nontemporal_store((acc + h[n * 64 + lane]) * dinv[n],
                                &y[(long long)n * 64 + lane]);
}

// ---- fused layer-3 GEMM + silu + chunk pool; 8 nodes/wave ----
__global__ __launch_bounds__(256) void k_xform3pool(const float* __restrict__ y,
                                                    const float* __restrict__ W,
                                                    const float* __restrict__ b,
                                                    const int* __restrict__ bounds,
                                                    float* __restrict__ partial) {
    __shared__ float4 Ws[64 * 64];          // 64KB: [k][lane] = W[k*256+4*lane..]
    __shared__ float4 ys4[X3T * 16];        // 32-node y tile (8KB)
    __shared__ float4 red[3][64];           // cross-wave pooled reduce (3KB)
    for (int i = threadIdx.x; i < 64 * 64; i += 256) Ws[i] = ((const float4*)W)[i];
    int lane = threadIdx.x & 63;
    int wave = threadIdx.x >> 6;
    int g = blockIdx.x / POOL_C;
    int c = blockIdx.x % POOL_C;
    int s = bounds[g], e = bounds[g + 1];
    int len = e - s;
    int cs = s + (int)((long long)len * c / POOL_C);
    int ce = s + (int)((long long)len * (c + 1) / POOL_C);
    float4 bv = ((const float4*)b)[lane];
    float4 pacc = make_float4(0.f, 0.f, 0.f, 0.f);
    int nb = wave * 8;   // this wave's first node within tile
    for (int base = cs; base < ce; base += X3T) {
        int tcnt = min(X3T, ce - base);
        __syncthreads();  // ys4 reuse (covers Ws on first iter)
        {
            const float4* ysrc = (const float4*)(y + (long long)base * 64);
            for (int i = threadIdx.x; i < tcnt * 16; i += 256) ys4[i] = ysrc[i];
        }
        __syncthreads();
        float4 acc[8];
#pragma unroll
        for (int i = 0; i < 8; i++) acc[i] = bv;
#pragma unroll 2
        for (int kq = 0; kq < 16; kq++) {
            float4 w0 = Ws[(4 * kq + 0) * 64 + lane];
            float4 w1 = Ws[(4 * kq + 1) * 64 + lane];
            float4 w2 = Ws[(4 * kq + 2) * 64 + lane];
            float4 w3 = Ws[(4 * kq + 3) * 64 + lane];
#pragma unroll
            for (int i = 0; i < 8; i++) {
                float4 yv = ys4[(nb + i) * 16 + kq];   // wave-uniform LDS broadcast
                fma4(acc[i], yv.x, w0); fma4(acc[i], yv.y, w1);
                fma4(acc[i], yv.z, w2); fma4(acc[i], yv.w, w3);
            }
        }
#pragma unroll
        for (int i = 0; i < 8; i++) {
            if (base + nb + i < ce) {
                pacc.x += silu_f(acc[i].x); pacc.y += silu_f(acc[i].y);
                pacc.z += silu_f(acc[i].z); pacc.w += silu_f(acc[i].w);
            }
        }
    }
    __syncthreads();
    if (wave > 0) red[wave - 1][lane] = pacc;
    __syncthreads();
    if (wave == 0) {
        float4 r0 = red[0][lane], r1 = red[1][lane], r2 = red[2][lane];
        pacc.x += r0.x + r1.x + r2.x;
        pacc.y += r0.y + r1.y + r2.y;
        pacc.z += r0.z + r1.z + r2.z;
        pacc.w += r0.w + r1.w + r2.w;
        ((float4*)partial)[(long long)blockIdx.x * 64 + lane] = pacc;
    }
}

// ---- pool stage 2 + MLP ----
__global__ __launch_bounds__(256) void k_mlp(const float* __restrict__ partial,
                                             const int* __restrict__ bounds,
                                             const float* __restrict__ L1,
                                             const float* __restrict__ c1,
                                             const float* __restrict__ L2,
                                             const float* __restrict__ c2,
                                             const float* __restrict__ L3,
                                             const float* __restrict__ c3,
                                             float* __restrict__ out) {
    __shared__ float pooled[256];
    __shared__ float z1[128];
    __shared__ float z2[64];
    int g = blockIdx.x;
    int t = threadIdx.x;
    int cnt = bounds[g + 1] - bounds[g];
    float s = 0.0f;
    for (int c = 0; c < POOL_C; c++) s += partial[((long long)g * POOL_C + c) * 256 + t];
    pooled[t] = s / (float)(cnt > 0 ? cnt : 1);
    __syncthreads();
    if (t < 128) {
        float acc = c1[t];
        for (int k = 0; k < 256; k++) acc += pooled[k] * L1[k * 128 + t];
        z1[t] = silu_f(acc);
    }
    __syncthreads();
    if (t < 64) {
        float acc = c2[t];
        for (int k = 0; k < 128; k++) acc += z1[k] * L2[k * 64 + t];
        z2[t] = silu_f(acc);
    }
    __syncthreads();
    if (t < 3) {
        float acc = c3[t];
        for (int k = 0; k < 64; k++) acc += z2[k] * L3[k * 3 + t];
        out[g * 3 + t] = acc;
    }
}

extern "C" void kernel_launch(void* const* d_in, const int* in_sizes, int n_in,
                              void* d_out, int out_size, void* d_ws, size_t ws_size,
                              hipStream_t stream) {
    const float* x     = (const float*)d_in[0];
    const int*   ei    = (const int*)d_in[1];
    const float* ea    = (const float*)d_in[2];
    const int*   batch = (const int*)d_in[3];
    const float* W1 = (const float*)d_in[4];
    const float* b1 = (const float*)d_in[5];
    const float* W2 = (const float*)d_in[6];
    const float* b2 = (const float*)d_in[7];
    const float* W3 = (const float*)d_in[8];
    const float* b3 = (const float*)d_in[9];
    const float* L1 = (const float*)d_in[10];
    const float* c1 = (const float*)d_in[11];
    const float* L2 = (const float*)d_in[12];
    const float* c2 = (const float*)d_in[13];
    const float* L3 = (const float*)d_in[14];
    const float* c3 = (const float*)d_in[15];
    float* out = (float*)d_out;

    const int N = in_sizes[0] / 16;
    const int E = in_sizes[2];
    const int G = out_size / 3;
    const int* src = ei;
    const int* dst = ei + E;
    const int B = (N + 255) >> 8;               // buckets (<=512)
    const int ept = (E + NBH * 256 - 1) / (NBH * 256);

    char* ws = (char*)d_ws;
    size_t off = 0;
    auto alloc = [&](size_t bytes) -> void* {
        void* p = (void*)(ws + off);
        off += (bytes + 255) & ~(size_t)255;
        return p;
    };
    float*        dinv    = (float*)alloc((size_t)N * 4);
    unsigned int* offs    = (unsigned int*)alloc((size_t)N * 4);
    int*          btotal  = (int*)  alloc(512 * 4);
    int*          bounds  = (int*)  alloc((size_t)(G + 1) * 4);
    int2*         ebuf    = (int2*) alloc((size_t)B * CAP * 8);   // padded buckets
    int2*         csr     = (int2*) alloc((size_t)B * CAP * 8);   // padded CSR
    float*        xp      = (float*)alloc((size_t)N * 16 * 4);
    float*        h1s     = (float*)alloc((size_t)N * 16 * 4);
    float*        h2s     = (float*)alloc((size_t)N * 64 * 4);
    float*        y64     = (float*)alloc((size_t)N * 64 * 4);
    float*        partial = (float*)alloc((size_t)G * POOL_C * 256 * 4);
    (void)ws_size;

    // ---- init, then single-kernel bucket scatter + node grouping ----
    k_init<<<1, 512, 0, stream>>>(batch, bounds, btotal, N, G);
    k_bscatter<<<NBH, 256, 0, stream>>>(src, dst, ea, btotal, ebuf, E, B, ept);
    k_bucket_csr<<<B, 256, 0, stream>>>(ebuf, btotal, csr, offs, dinv, x, xp, N);

    // ---- layer 1 (fused gather+xform) ----
    k_gx1<<<(N + 3) / 4, 256, 0, stream>>>(xp, csr, offs, dinv, W1, b1, h1s, N);

    // ---- layer 2 (fused gather+xform) ----
    k_gx2<<<(N + 3) / 4, 256, 0, stream>>>(h1s, csr, offs, dinv, W2, b2, h2s, N);

    // ---- layer 3: gather, then fused GEMM+silu+pool (h3 never written) ----
    k_gather64<<<(N + 3) / 4, 256, 0, stream>>>(h2s, csr, offs, dinv, y64, N);
    k_xform3pool<<<G * POOL_C, 256, 0, stream>>>(y64, W3, b3, bounds, partial);

    // ---- MLP head ----
    k_mlp<<<G, 256, 0, stream>>>(partial, bounds, L1, c1, L2, c2, L3, c3, out);
}

// Round 14
// 535.241 us; speedup vs baseline: 1.3221x; 1.3221x over previous
//
#include <hip/hip_runtime.h>
#include <math.h>

// ---------------------------------------------------------------------------
// GNN: 3x GCNConv(edge-weighted, self-loops) + SiLU, mean-pool, MLP.
// R1: CSR-by-dst + gather.  R2: two-stage pool.  R3: scaled features h'=h*dinv.
// R5: register-disciplined layer-3 GEMM.  R6: counting-sort CSR build.
// R7: fused layer3 GEMM+pool; gather+xform1/2 fused.  R8: POOL_C=8.
// R9: dl packed in ebuf.x[31:24].  R10: gx contiguous quarters ILP8; 8n/wave GEMM.
// R11: fixed-capacity padded buckets; offs packed pos|(len<<24).  [540.5 us]
// R12: nt-hint experiment REGRESSED (707 us): nt stores bypass L2 write-
//      combining -> scattered 8B stores became partial-line HBM writes
//      (bscatter WRITE_SIZE 26->129MB). R13: full revert to R11.
// ---------------------------------------------------------------------------

#define NBH 256       // scatter blocks
#define POOL_C 8      // chunks per graph for fused GEMM+pool (512 blocks = 2/CU)
#define X3T 32        // nodes per tile in xform3pool (8 per wave)
#define CAP 10240     // padded bucket capacity (mean 8184, sigma~90)

__device__ __forceinline__ float silu_f(float v) { return v / (1.0f + expf(-v)); }
__device__ __forceinline__ void fma4(float4& a, float s, const float4& w) {
    a.x += s * w.x; a.y += s * w.y; a.z += s * w.z; a.w += s * w.w;
}

// ---- init: zero bucket cursors + graph boundaries (one tiny block) ----
__global__ void k_init(const int* __restrict__ batch, int* __restrict__ bounds,
                       int* __restrict__ btotal, int N, int G) {
    int t = threadIdx.x;
    btotal[t] = 0;                     // 512 threads, 512 ints
    if (t > G) return;
    if (t == G) { bounds[G] = N; return; }
    int lo = 0, hi = N;
    while (lo < hi) { int m = (lo + hi) >> 1; if (batch[m] < t) lo = m + 1; else hi = m; }
    bounds[t] = lo;
}

// ---- count + reserve + scatter into statically-based padded buckets ----
// Pass 1: LDS histogram of this block's edge slice. Reserve: one global
// atomic per (block,bucket). Pass 2: scatter via LDS cursors (dst re-read
// is L2-warm). dst low byte packed into ebuf.x[31:24].
__global__ __launch_bounds__(256) void k_bscatter(const int* __restrict__ src,
                                                  const int* __restrict__ dst,
                                                  const float* __restrict__ ew,
                                                  int* __restrict__ btotal,
                                                  int2* __restrict__ ebuf,
                                                  int E, int B, int ept) {
    __shared__ int hist[512];
    __shared__ int cur[512];
    int blk = blockIdx.x, t = threadIdx.x;
    for (int i = t; i < B; i += 256) hist[i] = 0;
    __syncthreads();
    int start = blk * 256 * ept;
    for (int j = 0; j < ept; j++) {
        int e = start + j * 256 + t;
        if (e < E) atomicAdd(&hist[dst[e] >> 8], 1);
    }
    __syncthreads();
    for (int b = t; b < B; b += 256)
        cur[b] = b * CAP + atomicAdd(&btotal[b], hist[b]);
    __syncthreads();
    for (int j = 0; j < ept; j++) {
        int e = start + j * 256 + t;
        if (e < E) {
            int d = dst[e];
            int b = d >> 8;
            int pos = atomicAdd(&cur[b], 1);
            if (pos < (b + 1) * CAP)   // 23-sigma margin; clamp for safety
                ebuf[pos] = make_int2(src[e] | ((d & 255) << 24), __float_as_int(ew[e]));
        }
    }
}

// ---- per-bucket node grouping -> padded CSR + packed offs + dinv + xp ----
__global__ __launch_bounds__(256) void k_bucket_csr(const int2* __restrict__ ebuf,
                                                    const int* __restrict__ btotal,
                                                    int2* __restrict__ csr,
                                                    unsigned int* __restrict__ offs,
                                                    float* __restrict__ dinv,
                                                    const float* __restrict__ x,
                                                    float* __restrict__ xp,
                                                    int N) {
    __shared__ int ncnt[256];
    __shared__ int excl[256];
    __shared__ float wsum[256];
    int b = blockIdx.x, t = threadIdx.x;
    int base = b * CAP;
    int end = base + min(btotal[b], CAP);
    ncnt[t] = 0;
    wsum[t] = 0.0f;
    __syncthreads();
    for (int i = base + t; i < end; i += 256)
        atomicAdd(&ncnt[(unsigned)ebuf[i].x >> 24], 1);
    __syncthreads();
    int v = ncnt[t];
    excl[t] = v;
    __syncthreads();
#pragma unroll
    for (int o = 1; o < 256; o <<= 1) {
        int x2 = (t >= o) ? excl[t - o] : 0;
        __syncthreads();
        excl[t] += x2;
        __syncthreads();
    }
    int ex = excl[t] - v;                 // exclusive prefix within bucket
    int n = (b << 8) + t;
    if (n < N) offs[n] = (unsigned)(base + ex) | ((unsigned)v << 24);
    __syncthreads();
    ncnt[t] = base + ex;                  // reuse as per-node cursor
    __syncthreads();
    for (int i = base + t; i < end; i += 256) {
        int2 ent = ebuf[i];
        int node = (unsigned)ent.x >> 24;
        int pos = atomicAdd(&ncnt[node], 1);
        csr[pos] = make_int2(ent.x & 0x00FFFFFF, ent.y);
        atomicAdd(&wsum[node], __int_as_float(ent.y));
    }
    __syncthreads();
    if (n < N) {
        float dv = 1.0f / sqrtf(1.0f + wsum[t]);
        dinv[n] = dv;
        const float4* xr = (const float4*)(x + (long long)n * 16);
        float4* xw = (float4*)(xp + (long long)n * 16);
#pragma unroll
        for (int j = 0; j < 4; j++) {
            float4 vv = xr[j];
            vv.x *= dv; vv.y *= dv; vv.z *= dv; vv.w *= dv;
            xw[j] = vv;
        }
    }
}

// ---- fused gather16 + 16->16 GEMM + silu: h1 = silu(y@W1+b1)*dinv ----
// Edge-group eg owns a CONTIGUOUS quarter of the row, ILP8.
__global__ __launch_bounds__(256) void k_gx1(const float* __restrict__ h,
                                             const int2* __restrict__ csr,
                                             const unsigned int* __restrict__ offs,
                                             const float* __restrict__ dinv,
                                             const float* __restrict__ W,
                                             const float* __restrict__ b,
                                             float* __restrict__ out, int N) {
    __shared__ float Ws[16 * 16];
    __shared__ float bs[16];
    if (threadIdx.x < 256) Ws[threadIdx.x] = W[threadIdx.x];
    if (threadIdx.x < 16) bs[threadIdx.x] = b[threadIdx.x];
    __syncthreads();
    int n = blockIdx.x * 4 + (threadIdx.x >> 6);
    n = __builtin_amdgcn_readfirstlane(n);
    if (n >= N) return;
    int lane = threadIdx.x & 63;
    int d = lane & 15, eg = lane >> 4;
    unsigned op = offs[n];
    int p0 = op & 0x00FFFFFF;
    int len = op >> 24;
    int qs = p0 + ((len * eg) >> 2);
    int qe = p0 + ((len * (eg + 1)) >> 2);
    float acc = 0.0f;
    int p = qs;
    for (; p + 7 < qe; p += 8) {
        int2 e0 = csr[p], e1 = csr[p + 1], e2 = csr[p + 2], e3 = csr[p + 3];
        int2 e4 = csr[p + 4], e5 = csr[p + 5], e6 = csr[p + 6], e7 = csr[p + 7];
        float v0 = h[e0.x * 16 + d], v1 = h[e1.x * 16 + d];
        float v2 = h[e2.x * 16 + d], v3 = h[e3.x * 16 + d];
        float v4 = h[e4.x * 16 + d], v5 = h[e5.x * 16 + d];
        float v6 = h[e6.x * 16 + d], v7 = h[e7.x * 16 + d];
        acc += __int_as_float(e0.y) * v0; acc += __int_as_float(e1.y) * v1;
        acc += __int_as_float(e2.y) * v2; acc += __int_as_float(e3.y) * v3;
        acc += __int_as_float(e4.y) * v4; acc += __int_as_float(e5.y) * v5;
        acc += __int_as_float(e6.y) * v6; acc += __int_as_float(e7.y) * v7;
    }
    if (p + 3 < qe) {
        int2 e0 = csr[p], e1 = csr[p + 1], e2 = csr[p + 2], e3 = csr[p + 3];
        float v0 = h[e0.x * 16 + d], v1 = h[e1.x * 16 + d];
        float v2 = h[e2.x * 16 + d], v3 = h[e3.x * 16 + d];
        acc += __int_as_float(e0.y) * v0; acc += __int_as_float(e1.y) * v1;
        acc += __int_as_float(e2.y) * v2; acc += __int_as_float(e3.y) * v3;
        p += 4;
    }
    if (p + 1 < qe) {
        int2 e0 = csr[p], e1 = csr[p + 1];
        acc += __int_as_float(e0.y) * h[e0.x * 16 + d];
        acc += __int_as_float(e1.y) * h[e1.x * 16 + d];
        p += 2;
    }
    if (p < qe) {
        int2 e0 = csr[p];
        acc += __int_as_float(e0.y) * h[e0.x * 16 + d];
    }
    acc += __shfl_down(acc, 32, 64);
    acc += __shfl_down(acc, 16, 64);
    float dv = dinv[n];
    float yv = (acc + ((lane < 16) ? h[n * 16 + lane] : 0.0f)) * dv;
    float o = bs[d];
#pragma unroll
    for (int k = 0; k < 16; k++) o += __shfl(yv, k, 64) * Ws[k * 16 + d];
    if (lane < 16) out[n * 16 + lane] = silu_f(o) * dv;
}

// ---- fused gather16 + 16->64 GEMM + silu: h2 = silu(y@W2+b2)*dinv ----
__global__ __launch_bounds__(256) void k_gx2(const float* __restrict__ h,
                                             const int2* __restrict__ csr,
                                             const unsigned int* __restrict__ offs,
                                             const float* __restrict__ dinv,
                                             const float* __restrict__ W,
                                             const float* __restrict__ b,
                                             float* __restrict__ out, int N) {
    __shared__ float Ws[16 * 64];
    __shared__ float bs[64];
    for (int i = threadIdx.x; i < 16 * 64; i += 256) Ws[i] = W[i];
    if (threadIdx.x < 64) bs[threadIdx.x] = b[threadIdx.x];
    __syncthreads();
    int n = blockIdx.x * 4 + (threadIdx.x >> 6);
    n = __builtin_amdgcn_readfirstlane(n);
    if (n >= N) return;
    int lane = threadIdx.x & 63;
    int d = lane & 15, eg = lane >> 4;
    unsigned op = offs[n];
    int p0 = op & 0x00FFFFFF;
    int len = op >> 24;
    int qs = p0 + ((len * eg) >> 2);
    int qe = p0 + ((len * (eg + 1)) >> 2);
    float acc = 0.0f;
    int p = qs;
    for (; p + 7 < qe; p += 8) {
        int2 e0 = csr[p], e1 = csr[p + 1], e2 = csr[p + 2], e3 = csr[p + 3];
        int2 e4 = csr[p + 4], e5 = csr[p + 5], e6 = csr[p + 6], e7 = csr[p + 7];
        float v0 = h[e0.x * 16 + d], v1 = h[e1.x * 16 + d];
        float v2 = h[e2.x * 16 + d], v3 = h[e3.x * 16 + d];
        float v4 = h[e4.x * 16 + d], v5 = h[e5.x * 16 + d];
        float v6 = h[e6.x * 16 + d], v7 = h[e7.x * 16 + d];
        acc += __int_as_float(e0.y) * v0; acc += __int_as_float(e1.y) * v1;
        acc += __int_as_float(e2.y) * v2; acc += __int_as_float(e3.y) * v3;
        acc += __int_as_float(e4.y) * v4; acc += __int_as_float(e5.y) * v5;
        acc += __int_as_float(e6.y) * v6; acc += __int_as_float(e7.y) * v7;
    }
    if (p + 3 < qe) {
        int2 e0 = csr[p], e1 = csr[p + 1], e2 = csr[p + 2], e3 = csr[p + 3];
        float v0 = h[e0.x * 16 + d], v1 = h[e1.x * 16 + d];
        float v2 = h[e2.x * 16 + d], v3 = h[e3.x * 16 + d];
        acc += __int_as_float(e0.y) * v0; acc += __int_as_float(e1.y) * v1;
        acc += __int_as_float(e2.y) * v2; acc += __int_as_float(e3.y) * v3;
        p += 4;
    }
    if (p + 1 < qe) {
        int2 e0 = csr[p], e1 = csr[p + 1];
        acc += __int_as_float(e0.y) * h[e0.x * 16 + d];
        acc += __int_as_float(e1.y) * h[e1.x * 16 + d];
        p += 2;
    }
    if (p < qe) {
        int2 e0 = csr[p];
        acc += __int_as_float(e0.y) * h[e0.x * 16 + d];
    }
    acc += __shfl_down(acc, 32, 64);
    acc += __shfl_down(acc, 16, 64);
    float dv = dinv[n];
    float yv = (acc + ((lane < 16) ? h[n * 16 + lane] : 0.0f)) * dv;
    float o = bs[lane];
#pragma unroll
    for (int k = 0; k < 16; k++) o += __shfl(yv, k, 64) * Ws[k * 64 + lane];
    out[(long long)n * 64 + lane] = silu_f(o) * dv;
}

// ---- gather D=64 + self term, ILP 8 main + ILP 4 tail ----
__global__ __launch_bounds__(256) void k_gather64(const float* __restrict__ h,
                                                  const int2* __restrict__ csr,
                                                  const unsigned int* __restrict__ offs,
                                                  const float* __restrict__ dinv,
                                                  float* __restrict__ y, int N) {
    int n = blockIdx.x * 4 + (threadIdx.x >> 6);
    n = __builtin_amdgcn_readfirstlane(n);
    if (n >= N) return;
    int lane = threadIdx.x & 63;
    unsigned op = offs[n];
    const int2* row = csr + (op & 0x00FFFFFF);
    int len = op >> 24;
    float acc = 0.0f;
    int j = 0;
    for (; j + 7 < len; j += 8) {
        int2 ee[8];
        float vv[8];
#pragma unroll
        for (int i = 0; i < 8; i++) ee[i] = row[j + i];
#pragma unroll
        for (int i = 0; i < 8; i++) vv[i] = h[ee[i].x * 64 + lane];
#pragma unroll
        for (int i = 0; i < 8; i++) acc += __int_as_float(ee[i].y) * vv[i];
    }
    if (j + 3 < len) {                     // ILP 4 tail
        int2 e0 = row[j], e1 = row[j + 1], e2 = row[j + 2], e3 = row[j + 3];
        float v0 = h[e0.x * 64 + lane];
        float v1 = h[e1.x * 64 + lane];
        float v2 = h[e2.x * 64 + lane];
        float v3 = h[e3.x * 64 + lane];
        acc += __int_as_float(e0.y) * v0;
        acc += __int_as_float(e1.y) * v1;
        acc += __int_as_float(e2.y) * v2;
        acc += __int_as_float(e3.y) * v3;
        j += 4;
    }
    for (; j < len; j++) {
        int2 e0 = row[j];
        acc += __int_as_float(e0.y) * h[e0.x * 64 + lane];
    }
    y[n * 64 + lane] = (acc + h[n * 64 + lane]) * dinv[n];
}

// ---- fused layer-3 GEMM + silu + chunk pool; 8 nodes/wave ----
__global__ __launch_bounds__(256) void k_xform3pool(const float* __restrict__ y,
                                                    const float* __restrict__ W,
                                                    const float* __restrict__ b,
                                                    const int* __restrict__ bounds,
                                                    float* __restrict__ partial) {
    __shared__ float4 Ws[64 * 64];          // 64KB: [k][lane] = W[k*256+4*lane..]
    __shared__ float4 ys4[X3T * 16];        // 32-node y tile (8KB)
    __shared__ float4 red[3][64];           // cross-wave pooled reduce (3KB)
    for (int i = threadIdx.x; i < 64 * 64; i += 256) Ws[i] = ((const float4*)W)[i];
    int lane = threadIdx.x & 63;
    int wave = threadIdx.x >> 6;
    int g = blockIdx.x / POOL_C;
    int c = blockIdx.x % POOL_C;
    int s = bounds[g], e = bounds[g + 1];
    int len = e - s;
    int cs = s + (int)((long long)len * c / POOL_C);
    int ce = s + (int)((long long)len * (c + 1) / POOL_C);
    float4 bv = ((const float4*)b)[lane];
    float4 pacc = make_float4(0.f, 0.f, 0.f, 0.f);
    int nb = wave * 8;   // this wave's first node within tile
    for (int base = cs; base < ce; base += X3T) {
        int tcnt = min(X3T, ce - base);
        __syncthreads();  // ys4 reuse (covers Ws on first iter)
        {
            const float4* ysrc = (const float4*)(y + (long long)base * 64);
            for (int i = threadIdx.x; i < tcnt * 16; i += 256) ys4[i] = ysrc[i];
        }
        __syncthreads();
        float4 acc[8];
#pragma unroll
        for (int i = 0; i < 8; i++) acc[i] = bv;
#pragma unroll 2
        for (int kq = 0; kq < 16; kq++) {
            float4 w0 = Ws[(4 * kq + 0) * 64 + lane];
            float4 w1 = Ws[(4 * kq + 1) * 64 + lane];
            float4 w2 = Ws[(4 * kq + 2) * 64 + lane];
            float4 w3 = Ws[(4 * kq + 3) * 64 + lane];
#pragma unroll
            for (int i = 0; i < 8; i++) {
                float4 yv = ys4[(nb + i) * 16 + kq];   // wave-uniform LDS broadcast
                fma4(acc[i], yv.x, w0); fma4(acc[i], yv.y, w1);
                fma4(acc[i], yv.z, w2); fma4(acc[i], yv.w, w3);
            }
        }
#pragma unroll
        for (int i = 0; i < 8; i++) {
            if (base + nb + i < ce) {
                pacc.x += silu_f(acc[i].x); pacc.y += silu_f(acc[i].y);
                pacc.z += silu_f(acc[i].z); pacc.w += silu_f(acc[i].w);
            }
        }
    }
    __syncthreads();
    if (wave > 0) red[wave - 1][lane] = pacc;
    __syncthreads();
    if (wave == 0) {
        float4 r0 = red[0][lane], r1 = red[1][lane], r2 = red[2][lane];
        pacc.x += r0.x + r1.x + r2.x;
        pacc.y += r0.y + r1.y + r2.y;
        pacc.z += r0.z + r1.z + r2.z;
        pacc.w += r0.w + r1.w + r2.w;
        ((float4*)partial)[(long long)blockIdx.x * 64 + lane] = pacc;
    }
}

// ---- pool stage 2 + MLP ----
__global__ __launch_bounds__(256) void k_mlp(const float* __restrict__ partial,
                                             const int* __restrict__ bounds,
                                             const float* __restrict__ L1,
                                             const float* __restrict__ c1,
                                             const float* __restrict__ L2,
                                             const float* __restrict__ c2,
                                             const float* __restrict__ L3,
                                             const float* __restrict__ c3,
                                             float* __restrict__ out) {
    __shared__ float pooled[256];
    __shared__ float z1[128];
    __shared__ float z2[64];
    int g = blockIdx.x;
    int t = threadIdx.x;
    int cnt = bounds[g + 1] - bounds[g];
    float s = 0.0f;
    for (int c = 0; c < POOL_C; c++) s += partial[((long long)g * POOL_C + c) * 256 + t];
    pooled[t] = s / (float)(cnt > 0 ? cnt : 1);
    __syncthreads();
    if (t < 128) {
        float acc = c1[t];
        for (int k = 0; k < 256; k++) acc += pooled[k] * L1[k * 128 + t];
        z1[t] = silu_f(acc);
    }
    __syncthreads();
    if (t < 64) {
        float acc = c2[t];
        for (int k = 0; k < 128; k++) acc += z1[k] * L2[k * 64 + t];
        z2[t] = silu_f(acc);
    }
    __syncthreads();
    if (t < 3) {
        float acc = c3[t];
        for (int k = 0; k < 64; k++) acc += z2[k] * L3[k * 3 + t];
        out[g * 3 + t] = acc;
    }
}

extern "C" void kernel_launch(void* const* d_in, const int* in_sizes, int n_in,
                              void* d_out, int out_size, void* d_ws, size_t ws_size,
                              hipStream_t stream) {
    const float* x     = (const float*)d_in[0];
    const int*   ei    = (const int*)d_in[1];
    const float* ea    = (const float*)d_in[2];
    const int*   batch = (const int*)d_in[3];
    const float* W1 = (const float*)d_in[4];
    const float* b1 = (const float*)d_in[5];
    const float* W2 = (const float*)d_in[6];
    const float* b2 = (const float*)d_in[7];
    const float* W3 = (const float*)d_in[8];
    const float* b3 = (const float*)d_in[9];
    const float* L1 = (const float*)d_in[10];
    const float* c1 = (const float*)d_in[11];
    const float* L2 = (const float*)d_in[12];
    const float* c2 = (const float*)d_in[13];
    const float* L3 = (const float*)d_in[14];
    const float* c3 = (const float*)d_in[15];
    float* out = (float*)d_out;

    const int N = in_sizes[0] / 16;
    const int E = in_sizes[2];
    const int G = out_size / 3;
    const int* src = ei;
    const int* dst = ei + E;
    const int B = (N + 255) >> 8;               // buckets (<=512)
    const int ept = (E + NBH * 256 - 1) / (NBH * 256);

    char* ws = (char*)d_ws;
    size_t off = 0;
    auto alloc = [&](size_t bytes) -> void* {
        void* p = (void*)(ws + off);
        off += (bytes + 255) & ~(size_t)255;
        return p;
    };
    float*        dinv    = (float*)alloc((size_t)N * 4);
    unsigned int* offs    = (unsigned int*)alloc((size_t)N * 4);
    int*          btotal  = (int*)  alloc(512 * 4);
    int*          bounds  = (int*)  alloc((size_t)(G + 1) * 4);
    int2*         ebuf    = (int2*) alloc((size_t)B * CAP * 8);   // padded buckets
    int2*         csr     = (int2*) alloc((size_t)B * CAP * 8);   // padded CSR
    float*        xp      = (float*)alloc((size_t)N * 16 * 4);
    float*        h1s     = (float*)alloc((size_t)N * 16 * 4);
    float*        h2s     = (float*)alloc((size_t)N * 64 * 4);
    float*        y64     = (float*)alloc((size_t)N * 64 * 4);
    float*        partial = (float*)alloc((size_t)G * POOL_C * 256 * 4);
    (void)ws_size;

    // ---- init, then single-kernel bucket scatter + node grouping ----
    k_init<<<1, 512, 0, stream>>>(batch, bounds, btotal, N, G);
    k_bscatter<<<NBH, 256, 0, stream>>>(src, dst, ea, btotal, ebuf, E, B, ept);
    k_bucket_csr<<<B, 256, 0, stream>>>(ebuf, btotal, csr, offs, dinv, x, xp, N);

    // ---- layer 1 (fused gather+xform) ----
    k_gx1<<<(N + 3) / 4, 256, 0, stream>>>(xp, csr, offs, dinv, W1, b1, h1s, N);

    // ---- layer 2 (fused gather+xform) ----
    k_gx2<<<(N + 3) / 4, 256, 0, stream>>>(h1s, csr, offs, dinv, W2, b2, h2s, N);

    // ---- layer 3: gather, then fused GEMM+silu+pool (h3 never written) ----
    k_gather64<<<(N + 3) / 4, 256, 0, stream>>>(h2s, csr, offs, dinv, y64, N);
    k_xform3pool<<<G * POOL_C, 256, 0, stream>>>(y64, W3, b3, bounds, partial);

    // ---- MLP head ----
    k_mlp<<<G, 256, 0, stream>>>(partial, bounds, L1, c1, L2, c2, L3, c3, out);
}